// Round 1
// baseline (3454.185 us; speedup 1.0000x reference)
//
#include <hip/hip_runtime.h>
#include <stdint.h>
#include <stddef.h>

#define TT   128
#define BB   1024
#define INN  75
#define HH   128
#define KXP  96
#define OUTN 256
#define DECN 9600
#define EPSB 1e-5f
#define NBLK 64

typedef short v8s __attribute__((ext_vector_type(8)));   // 8 bf16 (4 VGPR) MFMA frag
typedef float v4f __attribute__((ext_vector_type(4)));   // 4 fp32 acc frag
typedef unsigned short ush;
typedef unsigned int   u32;
typedef unsigned long long u64;

// ---- static device workspace (fully rewritten every launch) ----
__device__ __align__(256) ush g_xpad[(size_t)TT * BB * KXP];   // x padded to K=96, [t][b][k] bf16
__device__ __align__(256) u64 g_G1[(size_t)TT * 32 * BB * 4];  // BN(x@Wih0)+b0, [t][g][row][16 bf16] (134 MB)
__device__ __align__(256) u64 g_h0s[(size_t)TT * BB * 32];     // h0 stream [t][row][128 bf16] as u64
__device__ __align__(256) u64 g_h1s[(size_t)TT * BB * 32];     // h1 stream
// weights [m][k] bf16, m permuted: origcol(m) = (m&3)*128 + (m>>4)*4 + ((m>>2)&3)
__device__ __align__(256) ush g_wtih0[512 * KXP];
__device__ __align__(256) ush g_wthh0[512 * HH];
__device__ __align__(256) ush g_wtih1[512 * HH];
__device__ __align__(256) ush g_wthh1[512 * HH];
__device__ __align__(256) ush g_fcwt[OUTN * HH];               // fc_w^T [col][k]
__device__ __align__(256) ush g_decwt[(size_t)DECN * OUTN];    // dec_w^T [col][k]
__device__ __align__(256) ush g_emb[BB * OUTN];                // fc output bf16
// grid-barrier state; invariant: at launch end g_flags[b] == g_bgen for all b
__device__ u32 g_flags[NBLK];
__device__ u32 g_bgen = 0;

// ---- helpers ----
__device__ __forceinline__ ush f2bf(float f) {
  u32 u = __float_as_uint(f);
  u32 r = (u + 0x7FFFu + ((u >> 16) & 1u)) >> 16;   // RNE
  return (ush)r;
}
__device__ __forceinline__ float bf2f(ush u) { return __uint_as_float(((u32)u) << 16); }
__device__ __forceinline__ float sigf(float x)  { return 1.f / (1.f + __expf(-x)); }
__device__ __forceinline__ float tanhf_(float x){ float e = __expf(2.f * x); return 1.f - 2.f / (e + 1.f); }
__device__ __forceinline__ v8s ld8(const ush* p) { return *reinterpret_cast<const v8s*>(p); }
__device__ __forceinline__ int origcol(int m) { return (m & 3) * 128 + (m >> 4) * 4 + ((m >> 2) & 3); }

// ---- device-wide barrier (64 blocks, all co-resident) ----
// Arrive: release-store own flag. Block 0: lanes 1..63 poll one flag each (parallel),
// then release-store the generation; followers spin on it. Relaxed polls (no per-poll
// L2 invalidate); one acquire fence on exit.
__device__ __forceinline__ void gridbar(u32 target) {
  __syncthreads();
  if (threadIdx.x == 0) {
    __threadfence();
    __hip_atomic_store(&g_flags[blockIdx.x], target, __ATOMIC_RELEASE, __HIP_MEMORY_SCOPE_AGENT);
  }
  if (blockIdx.x == 0) {
    const int t = threadIdx.x;
    if (t >= 1 && t < NBLK) {
      while (__hip_atomic_load(&g_flags[t], __ATOMIC_RELAXED, __HIP_MEMORY_SCOPE_AGENT) < target)
        __builtin_amdgcn_s_sleep(8);
    }
    __syncthreads();
    if (t == 0) {
      __hip_atomic_store(&g_bgen, target, __ATOMIC_RELEASE, __HIP_MEMORY_SCOPE_AGENT);
      __threadfence();
    }
  } else {
    if (threadIdx.x == 0) {
      while (__hip_atomic_load(&g_bgen, __ATOMIC_RELAXED, __HIP_MEMORY_SCOPE_AGENT) < target)
        __builtin_amdgcn_s_sleep(8);
      __threadfence();
    }
  }
  __syncthreads();
}

// ---- prep kernels ----
__global__ void kpackx(const float* __restrict__ seq) {
  int idx = blockIdx.x * 256 + threadIdx.x;   // < TT*BB*KXP
  int kk = idx % KXP; int rest = idx / KXP;
  int b = rest % BB;  int t = rest / BB;
  float v = (kk < INN) ? seq[((size_t)b * TT + t) * INN + kk] : 0.f;
  g_xpad[idx] = f2bf(v);
}

__global__ void kpackw(const float* __restrict__ Wih0, const float* __restrict__ Whh0,
                       const float* __restrict__ Wih1, const float* __restrict__ Whh1,
                       const float* __restrict__ fcw,  const float* __restrict__ decw) {
  int idx = blockIdx.x * 256 + threadIdx.x;   // grid 10688
  if (idx < 49152) {                          // wtih0: [m][96]
    int m = idx / KXP, k = idx % KXP;
    g_wtih0[idx] = f2bf((k < INN) ? Wih0[k * 512 + origcol(m)] : 0.f);
  } else if (idx < 114688) {
    int j = idx - 49152; int m = j / HH, k = j % HH;
    g_wthh0[j] = f2bf(Whh0[k * 512 + origcol(m)]);
  } else if (idx < 180224) {
    int j = idx - 114688; int m = j / HH, k = j % HH;
    g_wtih1[j] = f2bf(Wih1[k * 512 + origcol(m)]);
  } else if (idx < 245760) {
    int j = idx - 180224; int m = j / HH, k = j % HH;
    g_wthh1[j] = f2bf(Whh1[k * 512 + origcol(m)]);
  } else if (idx < 278528) {                  // fcwt [c][128]
    int j = idx - 245760; int c = j / HH, k = j % HH;
    g_fcwt[j] = f2bf(fcw[k * OUTN + c]);
  } else {                                    // decwt [c][256], coalesced reads
    int j = idx - 278528; int n = j % DECN, k = j / DECN;
    g_decwt[(size_t)n * OUTN + k] = f2bf(decw[(size_t)k * DECN + n]);
  }
}

// G1[t][g][row][16] = BN_ih0(x_t @ Wih0) + b0 (folded), transposed-MFMA orientation.
__global__ __launch_bounds__(512) void kprep(const float* __restrict__ gih0,
                                             const float* __restrict__ bih0,
                                             const float* __restrict__ b0) {
  const int t = blockIdx.x >> 3, ct = blockIdx.x & 7;
  const int tid = threadIdx.x, wv = tid >> 6, l = tid & 63;
  const int lm = l & 15, lq = l >> 4;
  const int R0 = wv * 128;
  __shared__ float sred[8][64][2];
  __shared__ float scoef[64][2];

  v8s af[4][3];
#pragma unroll
  for (int tt = 0; tt < 4; ++tt)
#pragma unroll
    for (int ks = 0; ks < 3; ++ks)
      af[tt][ks] = ld8(&g_wtih0[(ct * 64 + tt * 16 + lm) * KXP + ks * 32 + lq * 8]);

  const v4f vz = {0.f, 0.f, 0.f, 0.f};
  v4f acc[8][4];
#pragma unroll
  for (int mt = 0; mt < 8; ++mt)
#pragma unroll
    for (int tt = 0; tt < 4; ++tt) acc[mt][tt] = vz;

#pragma unroll
  for (int mt = 0; mt < 8; ++mt) {
    const ush* xr = g_xpad + ((size_t)t * BB + R0 + mt * 16 + lm) * KXP + lq * 8;
    v8s bx0 = ld8(xr), bx1 = ld8(xr + 32), bx2 = ld8(xr + 64);
#pragma unroll
    for (int tt = 0; tt < 4; ++tt) {
      acc[mt][tt] = __builtin_amdgcn_mfma_f32_16x16x32_bf16(af[tt][0], bx0, acc[mt][tt], 0, 0, 0);
      acc[mt][tt] = __builtin_amdgcn_mfma_f32_16x16x32_bf16(af[tt][1], bx1, acc[mt][tt], 0, 0, 0);
      acc[mt][tt] = __builtin_amdgcn_mfma_f32_16x16x32_bf16(af[tt][2], bx2, acc[mt][tt], 0, 0, 0);
    }
  }
  float S[4][4], Q[4][4];
#pragma unroll
  for (int tt = 0; tt < 4; ++tt)
#pragma unroll
    for (int r = 0; r < 4; ++r) {
      float s = 0.f, q = 0.f;
#pragma unroll
      for (int mt = 0; mt < 8; ++mt) { float a = acc[mt][tt][r]; s += a; q += a * a; }
#pragma unroll
      for (int off = 1; off < 16; off <<= 1) { s += __shfl_xor(s, off); q += __shfl_xor(q, off); }
      S[tt][r] = s; Q[tt][r] = q;
    }
  if (lm == 0)
#pragma unroll
    for (int tt = 0; tt < 4; ++tt)
#pragma unroll
      for (int r = 0; r < 4; ++r) {
        sred[wv][tt * 16 + lq * 4 + r][0] = S[tt][r];
        sred[wv][tt * 16 + lq * 4 + r][1] = Q[tt][r];
      }
  __syncthreads();
  if (tid < 64) {
    float Sa = 0.f, Qa = 0.f;
#pragma unroll
    for (int w8 = 0; w8 < 8; ++w8) { Sa += sred[w8][tid][0]; Qa += sred[w8][tid][1]; }
    int oc = origcol(ct * 64 + tid);
    float m_ = Sa * (1.f / BB), v_ = Qa * (1.f / BB) - m_ * m_;
    float A = gih0[oc] * rsqrtf(v_ + EPSB);
    scoef[tid][0] = A; scoef[tid][1] = bih0[oc] - A * m_ + b0[oc];
  }
  __syncthreads();
  float CA[4][4], CD[4][4];
#pragma unroll
  for (int tt = 0; tt < 4; ++tt)
#pragma unroll
    for (int r = 0; r < 4; ++r) {
      CA[tt][r] = scoef[tt * 16 + lq * 4 + r][0];
      CD[tt][r] = scoef[tt * 16 + lq * 4 + r][1];
    }
#pragma unroll
  for (int mt = 0; mt < 8; ++mt) {
    const int row = R0 + mt * 16 + lm;
#pragma unroll
    for (int tt = 0; tt < 4; ++tt) {
      const int g = ct * 4 + tt;
      u32 lo = (u32)f2bf(CA[tt][0] * acc[mt][tt][0] + CD[tt][0])
             | ((u32)f2bf(CA[tt][1] * acc[mt][tt][1] + CD[tt][1]) << 16);
      u32 hi = (u32)f2bf(CA[tt][2] * acc[mt][tt][2] + CD[tt][2])
             | ((u32)f2bf(CA[tt][3] * acc[mt][tt][3] + CD[tt][3]) << 16);
      g_G1[(((size_t)t * 32 + g) * BB + row) * 4 + lq] = (u64)lo | ((u64)hi << 32);
    }
  }
}

// ---- krec: the whole 2-layer recurrence in ONE persistent kernel.
// 64 blocks x 512 thr. Block = (L = b>>5, col-group g = b&31 -> units 4g..4g+3).
// Each block owns ALL 1024 batch rows for its 16 m-cols -> every BN reduction is
// block-local; the only cross-block dependency is the h streams -> 1 gridbar/step.
// Lane: row = wv*128 + mt*16 + lm, unit = g*4+lq, gate = r. c-state lives in VGPRs
// across all steps; P never touches global memory.
__global__ __launch_bounds__(512, 2) void krec(
    const float* __restrict__ ghh0, const float* __restrict__ bhh0,
    const float* __restrict__ gc0,  const float* __restrict__ bc0,
    const float* __restrict__ gih1, const float* __restrict__ bih1,
    const float* __restrict__ ghh1, const float* __restrict__ bhh1,
    const float* __restrict__ b1,   const float* __restrict__ gc1,
    const float* __restrict__ bc1) {
  const int L = blockIdx.x >> 5, g = blockIdx.x & 31;
  const int tid = threadIdx.x, wv = tid >> 6, l = tid & 63;
  const int lm = l & 15, lq = l >> 4;

  __shared__ float sred[8][16][4];
  __shared__ float scoef[16][3];
  __shared__ float scred[8][4][2];
  __shared__ float sccoef[4][2];
  __shared__ u32 sbase;

  if (tid == 0) sbase = __hip_atomic_load(&g_bgen, __ATOMIC_RELAXED, __HIP_MEMORY_SCOPE_AGENT);
  __syncthreads();
  const u32 base = sbase;   // barrier generation base; safe: g_bgen can't advance
                            // until every block has arrived at barrier 0.

  // persistent weight fragments: L0 -> Whh0 ; L1 -> Wih1 (A) + Whh1 (B)
  v8s afA[4], afB[4];
  const ush* wA = (L == 0) ? g_wthh0 : g_wtih1;
#pragma unroll
  for (int ks = 0; ks < 4; ++ks) {
    afA[ks] = ld8(&wA[(g * 16 + lm) * HH + ks * 32 + lq * 8]);
    afB[ks] = ld8(&g_wthh1[(g * 16 + lm) * HH + ks * 32 + lq * 8]);
  }

  const ush* const h0r = reinterpret_cast<const ush*>(g_h0s);
  const ush* const h1r = reinterpret_cast<const ush*>(g_h1s);
  float cst[8];   // persistent c-state (8 rows per lane)
  float so_[8];

#pragma unroll 1
  for (int s = 0; s <= TT; ++s) {
    const bool act = (L == 0) ? (s < TT) : (s >= 1);
    if (act) {
      const v4f vz = {0.f, 0.f, 0.f, 0.f};
      v4f PA[8], PB[8];
#pragma unroll
      for (int mt = 0; mt < 8; ++mt) { PA[mt] = vz; PB[mt] = vz; }

      // GEMM: PA = W_A^T tile @ h0[s-1]; PB = Whh1^T tile @ h1[s-2] (L1 only)
      if ((L == 1) || (s >= 1)) {
        const ush* hb = h0r + (size_t)(s - 1) * BB * HH;
#pragma unroll
        for (int mt = 0; mt < 8; ++mt) {
          const ush* hp = hb + (size_t)(wv * 128 + mt * 16 + lm) * HH + lq * 8;
#pragma unroll
          for (int ks = 0; ks < 4; ++ks)
            PA[mt] = __builtin_amdgcn_mfma_f32_16x16x32_bf16(afA[ks], ld8(hp + ks * 32), PA[mt], 0, 0, 0);
        }
      }
      if (L == 1 && s >= 2) {
        const ush* hb = h1r + (size_t)(s - 2) * BB * HH;
#pragma unroll
        for (int mt = 0; mt < 8; ++mt) {
          const ush* hp = hb + (size_t)(wv * 128 + mt * 16 + lm) * HH + lq * 8;
#pragma unroll
          for (int ks = 0; ks < 4; ++ks)
            PB[mt] = __builtin_amdgcn_mfma_f32_16x16x32_bf16(afB[ks], ld8(hp + ks * 32), PB[mt], 0, 0, 0);
        }
      }

      // ---- block-local gate-BN stats (over all 1024 rows) ----
      float sA[4], qA[4], sB[4], qB[4];
#pragma unroll
      for (int r = 0; r < 4; ++r) {
        float s1 = 0.f, q1 = 0.f, s2 = 0.f, q2 = 0.f;
#pragma unroll
        for (int mt = 0; mt < 8; ++mt) {
          const float a = PA[mt][r]; s1 += a; q1 += a * a;
          const float b = PB[mt][r]; s2 += b; q2 += b * b;
        }
#pragma unroll
        for (int off = 1; off < 16; off <<= 1) {
          s1 += __shfl_xor(s1, off); q1 += __shfl_xor(q1, off);
          s2 += __shfl_xor(s2, off); q2 += __shfl_xor(q2, off);
        }
        sA[r] = s1; qA[r] = q1; sB[r] = s2; qB[r] = q2;
      }
      if (lm == 0)
#pragma unroll
        for (int r = 0; r < 4; ++r) {
          sred[wv][lq * 4 + r][0] = sA[r]; sred[wv][lq * 4 + r][1] = qA[r];
          sred[wv][lq * 4 + r][2] = sB[r]; sred[wv][lq * 4 + r][3] = qB[r];
        }
      __syncthreads();
      if (tid < 16) {
        float S1 = 0.f, Q1 = 0.f, S2 = 0.f, Q2 = 0.f;
#pragma unroll
        for (int w = 0; w < 8; ++w) {
          S1 += sred[w][tid][0]; Q1 += sred[w][tid][1];
          S2 += sred[w][tid][2]; Q2 += sred[w][tid][3];
        }
        const int oc = origcol(g * 16 + tid);
        if (L == 0) {
          const float m_ = S1 * (1.f / BB), v_ = Q1 * (1.f / BB) - m_ * m_;
          const float Ah = ghh0[oc] * rsqrtf(v_ + EPSB);
          scoef[tid][0] = Ah; scoef[tid][1] = bhh0[oc] - Ah * m_; scoef[tid][2] = 0.f;
        } else {
          const float m1 = S1 * (1.f / BB), v1 = Q1 * (1.f / BB) - m1 * m1;
          const float Ai = gih1[oc] * rsqrtf(v1 + EPSB);
          const float m2 = S2 * (1.f / BB), v2 = Q2 * (1.f / BB) - m2 * m2;
          const float Ah = ghh1[oc] * rsqrtf(v2 + EPSB);
          scoef[tid][0] = Ai; scoef[tid][1] = Ah;
          scoef[tid][2] = bih1[oc] - Ai * m1 + bhh1[oc] - Ah * m2 + b1[oc];
        }
      }
      __syncthreads();
      float C0[4], C1a[4], C2[4];
#pragma unroll
      for (int r = 0; r < 4; ++r) {
        C0[r]  = scoef[lq * 4 + r][0];
        C1a[r] = scoef[lq * 4 + r][1];
        C2[r]  = scoef[lq * 4 + r][2];
      }

      // ---- pointwise + c update (c in registers) ----
      const bool first = (L == 0) ? (s == 0) : (s == 1);
      float cS = 0.f, cQ = 0.f;
#pragma unroll
      for (int mt = 0; mt < 8; ++mt) {
        const int row = wv * 128 + mt * 16 + lm;
        float gv0, gv1, gv2, gv3;
        if (L == 0) {
          const u64 g1 = g_G1[(((size_t)s * 32 + g) * BB + row) * 4 + lq];
          gv0 = bf2f((ush)g1)         + C0[0] * PA[mt][0] + C1a[0];
          gv1 = bf2f((ush)(g1 >> 16)) + C0[1] * PA[mt][1] + C1a[1];
          gv2 = bf2f((ush)(g1 >> 32)) + C0[2] * PA[mt][2] + C1a[2];
          gv3 = bf2f((ush)(g1 >> 48)) + C0[3] * PA[mt][3] + C1a[3];
        } else {
          gv0 = C0[0] * PA[mt][0] + C1a[0] * PB[mt][0] + C2[0];
          gv1 = C0[1] * PA[mt][1] + C1a[1] * PB[mt][1] + C2[1];
          gv2 = C0[2] * PA[mt][2] + C1a[2] * PB[mt][2] + C2[2];
          gv3 = C0[3] * PA[mt][3] + C1a[3] * PB[mt][3] + C2[3];
        }
        const float cold = first ? 0.f : cst[mt];
        const float c1 = sigf(gv0) * cold + sigf(gv1) * tanhf_(gv3);
        cst[mt] = c1; so_[mt] = sigf(gv2);
        cS += c1; cQ += c1 * c1;
      }

      // ---- block-local c-BN ----
#pragma unroll
      for (int off = 1; off < 16; off <<= 1) { cS += __shfl_xor(cS, off); cQ += __shfl_xor(cQ, off); }
      if (lm == 0) { scred[wv][lq][0] = cS; scred[wv][lq][1] = cQ; }
      __syncthreads();
      if (tid < 4) {
        float S = 0.f, Q = 0.f;
#pragma unroll
        for (int w = 0; w < 8; ++w) { S += scred[w][tid][0]; Q += scred[w][tid][1]; }
        const float m_ = S * (1.f / BB), v_ = Q * (1.f / BB) - m_ * m_;
        const int uu = g * 4 + tid;
        const float gcv = (L == 0) ? gc0[uu] : gc1[uu];
        const float bcv = (L == 0) ? bc0[uu] : bc1[uu];
        const float ac = gcv * rsqrtf(v_ + EPSB);
        sccoef[tid][0] = ac; sccoef[tid][1] = bcv - ac * m_;
      }
      __syncthreads();
      const float ac = sccoef[lq][0], dc = sccoef[lq][1];

      // ---- h output: pack 4 units across lq lanes -> u64 store per row ----
      u64* hdst = (L == 0) ? &g_h0s[(size_t)s * BB * 32] : &g_h1s[(size_t)(s - 1) * BB * 32];
#pragma unroll
      for (int mt = 0; mt < 8; ++mt) {
        const int row = wv * 128 + mt * 16 + lm;
        const u32 v = (u32)f2bf(so_[mt] * tanhf_(ac * cst[mt] + dc));
        const u32 a = v | (__shfl_xor(v, 16) << 16);   // valid on lq even
        const u32 b = __shfl_xor(a, 32);               // lq0 <- (u2,u3)
        if (lq == 0) hdst[(size_t)row * 32 + g] = (u64)a | ((u64)b << 32);
      }
    }
    if (s < TT) gridbar(base + (u32)s + 1);
  }
}

// ---- epilogue: emb = h1(T-1) @ fc_w + fc_b (bf16 out) ----
__global__ __launch_bounds__(256) void kfc(const float* __restrict__ fcb) {
  const int tid = threadIdx.x, w = tid >> 6, l = tid & 63;
  const int lm = l & 15, lq = l >> 4;
  const int col = blockIdx.x * 16 + lm;   // grid 16
  const ush* hsrc = reinterpret_cast<const ush*>(g_h1s) + (size_t)(TT - 1) * BB * HH;
  v8s bf[4];
#pragma unroll
  for (int ks = 0; ks < 4; ++ks) bf[ks] = ld8(&g_fcwt[col * HH + ks * 32 + lq * 8]);
  const float bias = fcb[col];
  const v4f vz = {0.f, 0.f, 0.f, 0.f};
#pragma unroll
  for (int mt = 0; mt < 16; ++mt) {
    const int rowa = w * 256 + mt * 16 + lm;
    const ush* ap = hsrc + (size_t)rowa * HH + lq * 8;
    v4f acc = vz;
#pragma unroll
    for (int ks = 0; ks < 4; ++ks)
      acc = __builtin_amdgcn_mfma_f32_16x16x32_bf16(ld8(ap + ks * 32), bf[ks], acc, 0, 0, 0);
#pragma unroll
    for (int r = 0; r < 4; ++r) {
      int row = w * 256 + mt * 16 + lq * 4 + r;
      g_emb[row * OUTN + col] = f2bf(acc[r] + bias);
    }
  }
}

// ---- epilogue: out = emb @ dec_w + dec_b, transposed MFMA -> 16B coalesced stores ----
__global__ __launch_bounds__(256) void kdec(const float* __restrict__ decb, float* __restrict__ out) {
  const int tid = threadIdx.x, wv = tid >> 6, l = tid & 63;
  const int lm = l & 15, lq = l >> 4;
  const int c0 = blockIdx.x * 16;         // grid 600
  const int R0 = wv * 256;
  v8s af[8];
#pragma unroll
  for (int ks = 0; ks < 8; ++ks) af[ks] = ld8(&g_decwt[(size_t)(c0 + lm) * OUTN + ks * 32 + lq * 8]);
  float bias[4];
#pragma unroll
  for (int r = 0; r < 4; ++r) bias[r] = decb[c0 + lq * 4 + r];
  const v4f vz = {0.f, 0.f, 0.f, 0.f};
#pragma unroll
  for (int mt = 0; mt < 16; ++mt) {
    const int row = R0 + mt * 16 + lm;
    const ush* bp = g_emb + (size_t)row * OUTN + lq * 8;
    v4f acc = vz;
#pragma unroll
    for (int ks = 0; ks < 8; ++ks)
      acc = __builtin_amdgcn_mfma_f32_16x16x32_bf16(af[ks], ld8(bp + ks * 32), acc, 0, 0, 0);
    v4f o;
#pragma unroll
    for (int r = 0; r < 4; ++r) o[r] = acc[r] + bias[r];
    *reinterpret_cast<v4f*>(&out[(size_t)row * DECN + c0 + lq * 4]) = o;
  }
}

extern "C" void kernel_launch(void* const* d_in, const int* in_sizes, int n_in,
                              void* d_out, int out_size, void* d_ws, size_t ws_size,
                              hipStream_t stream) {
  const float* seq  = (const float*)d_in[0];
  const float* Wih0 = (const float*)d_in[1];
  const float* Whh0 = (const float*)d_in[2];
  const float* b0   = (const float*)d_in[3];
  const float* gih0 = (const float*)d_in[4];
  const float* bih0 = (const float*)d_in[5];
  const float* ghh0 = (const float*)d_in[6];
  const float* bhh0 = (const float*)d_in[7];
  const float* gc0  = (const float*)d_in[8];
  const float* bc0  = (const float*)d_in[9];
  const float* Wih1 = (const float*)d_in[10];
  const float* Whh1 = (const float*)d_in[11];
  const float* b1   = (const float*)d_in[12];
  const float* gih1 = (const float*)d_in[13];
  const float* bih1 = (const float*)d_in[14];
  const float* ghh1 = (const float*)d_in[15];
  const float* bhh1 = (const float*)d_in[16];
  const float* gc1  = (const float*)d_in[17];
  const float* bc1  = (const float*)d_in[18];
  const float* fcw  = (const float*)d_in[19];
  const float* fcb  = (const float*)d_in[20];
  const float* decw = (const float*)d_in[21];
  const float* decb = (const float*)d_in[22];
  float* out = (float*)d_out;
  (void)in_sizes; (void)n_in; (void)out_size; (void)d_ws; (void)ws_size;

  kpackx<<<dim3((TT * BB * KXP) / 256), dim3(256), 0, stream>>>(seq);
  kpackw<<<dim3(10688), dim3(256), 0, stream>>>(Wih0, Whh0, Wih1, Whh1, fcw, decw);
  kprep<<<dim3(TT * 8), dim3(512), 0, stream>>>(gih0, bih0, b0);
  krec<<<dim3(NBLK), dim3(512), 0, stream>>>(ghh0, bhh0, gc0, bc0,
                                             gih1, bih1, ghh1, bhh1, b1, gc1, bc1);
  kfc<<<dim3(16), dim3(256), 0, stream>>>(fcb);
  kdec<<<dim3(600), dim3(256), 0, stream>>>(decb, out);
}